// Round 7
// baseline (212.113 us; speedup 1.0000x reference)
//
#include <hip/hip_runtime.h>

// CustomConv2d: 3x3 conv, stride 1, pad 1. B=32, Cin=128, H=W=56, Cout=256.
// fp32 in/out (round-1 NaN proved it); per-wave dtype self-detection keeps
// robustness without a separate serialized detect dispatch.
//
// Implicit GEMM, internally bf16. M=cout(256), N=b*h*w(100352), K=cin*9(1152).
// Round-12: rounds 10/11 (register-A + hand-counted vmcnt + inline-asm
// loads) died twice with container failures; can't distinguish infra from
// kernel-induced death, so this round keeps the A-removal insight but drops
// every fragile construct:
//   - wt in FRAGMENT ORDER (wt_repack): a wave's MFMA A-operand is one
//     coalesced 1KB load of L2-resident data (576KB total, shared by all
//     784 blocks) -> A never touches LDS (round-9 spent 2/3 of its LDS
//     traffic + barrier pressure re-staging identical A data 36x/block)
//   - A prefetched one half ahead into registers as PLAIN C++ short8 loads:
//     compiler tracks the waits, no manual vmcnt ledger to invalidate
//   - B staging via global_load_lds, 2-deep double buffer (2 x 8KB LDS);
//     one conservative vmcnt(0)+barrier per half (superset drain - always
//     correct), issued-early loads get ~600cyc MFMA cover
//   - 16KB LDS -> reg-limited occupancy (acc 128 AGPR + ~110 VGPR), 2-3
//     blocks/CU; unsynchronized blocks fill each other's drain bubbles
//   - same B XOR chunk swizzle (0 bank conflicts measured), XCD swizzle

typedef __attribute__((ext_vector_type(8))) short short8;
typedef __attribute__((ext_vector_type(4))) float floatx4;

typedef __attribute__((address_space(1))) const void* gas_ptr;
typedef __attribute__((address_space(3))) void* las_ptr;

__device__ static inline void gl2lds16(const void* g, void* l) {
    __builtin_amdgcn_global_load_lds((gas_ptr)g, (las_ptr)l, 16, 0, 0);
}

__device__ static inline float bf2f(unsigned short u) {
    union { unsigned int i; float f; } x; x.i = ((unsigned int)u) << 16; return x.f;
}
__device__ static inline unsigned short f2bf(float f) {
    union { float f; unsigned int i; } x; x.f = f;
    unsigned int r = (x.i + 0x7FFFu + ((x.i >> 16) & 1u)) >> 16;  // RNE
    return (unsigned short)r;
}

// Per-wave dtype sniff: low halves of fp32 words are random mantissa bits
// (~19% plausible bf16 exponents); true bf16 data is ~100% plausible.
// Uniform across the wave via ballot; requires all 64 lanes active.
__device__ static inline bool wave_detect_bf16(const unsigned int* __restrict__ p) {
    const int lane = threadIdx.x & 63;
    int cnt = 0;
#pragma unroll
    for (int r = 0; r < 4; ++r) {
        unsigned int w = p[r * 64 + lane];
        unsigned short lo = (unsigned short)(w & 0xFFFFu);
        int e = (lo >> 7) & 0xFF;
        bool plaus = (lo == 0) || (e >= 96 && e <= 144);
        cnt += (int)__popcll(__ballot(plaus));
    }
    return cnt >= 205;   // >=80% of 256 sampled halves
}

// ------ weight repack -> fragment order [36][2][8][64] 16B chunks ---------
// Chunk (h=off*4+q, wm, i, lane) holds A[co=wm*128+i*16+(lane&15)]
// [ci=q*32+(lane>>4)*8 .. +8) as 8 bf16. conv_mfma lane l then loads its
// MFMA A-fragment at ushort index h*8192 + wm*4096 + i*512 + l*8.
__global__ void wt_repack(const void* __restrict__ wsrc,
                          unsigned short* __restrict__ wt) {
    const bool isbf = wave_detect_bf16((const unsigned int*)wsrc);
    int idx  = blockIdx.x * 256 + threadIdx.x;   // 36864 chunks, grid=144
    int lane = idx & 63;
    int i    = (idx >> 6) & 7;
    int wm   = (idx >> 9) & 1;
    int q    = (idx >> 10) & 3;
    int off  = idx >> 12;                        // 0..8 = dh*3+dw
    int co   = wm * 128 + i * 16 + (lane & 15);
    int ci0  = q * 32 + (lane >> 4) * 8;
    union { unsigned short s[8]; uint4 u; } pk;
#pragma unroll
    for (int e = 0; e < 8; ++e) {
        size_t s = (size_t)(co * 128 + ci0 + e) * 9 + off;
        float v = isbf ? bf2f(((const unsigned short*)wsrc)[s])
                       : ((const float*)wsrc)[s];
        pk.s[e] = f2bf(v);
    }
    *(uint4*)(wt + (size_t)idx * 8) = pk.u;
}

// ------- x NCHW -> padded NHWC bf16 [32][58][58][128], LDS transpose -------
__global__ __launch_bounds__(256) void x_repack(
    const void* __restrict__ xsrc, unsigned short* __restrict__ xp) {
    __shared__ unsigned short tile[56 * 130];   // pad 130: conflict-free
    const int bh  = blockIdx.x;                 // 32*58 blocks
    const int b   = bh / 58, hp = bh - b * 58;  // hp in [0,58)
    const int tid = threadIdx.x;
    unsigned short* row = xp + (size_t)(b * 58 + hp) * 58 * 128;
    if (hp == 0 || hp == 57) {                  // top/bottom pad rows
        uint4 z; z.x = z.y = z.z = z.w = 0u;
        uint4* r = (uint4*)row;
        for (int t = tid; t < 928; t += 256) r[t] = z;
        return;
    }
    const bool isbf = wave_detect_bf16((const unsigned int*)xsrc);
    const int h = hp - 1;
    if (isbf) {
        const unsigned short* xs =
            (const unsigned short*)xsrc + (size_t)b * 128 * 3136 + h * 56;
#pragma unroll
        for (int it = 0; it < 7; ++it) {        // 1792 items = 128ci x 14 w4
            int idx = it * 256 + tid;
            int ci = idx / 14, w4 = idx - ci * 14;
            ushort4 v = *(const ushort4*)(xs + (size_t)ci * 3136 + w4 * 4);
            tile[(w4 * 4 + 0) * 130 + ci] = v.x;
            tile[(w4 * 4 + 1) * 130 + ci] = v.y;
            tile[(w4 * 4 + 2) * 130 + ci] = v.z;
            tile[(w4 * 4 + 3) * 130 + ci] = v.w;
        }
    } else {
        const float* xs = (const float*)xsrc + (size_t)b * 128 * 3136 + h * 56;
#pragma unroll
        for (int it = 0; it < 7; ++it) {
            int idx = it * 256 + tid;
            int ci = idx / 14, w4 = idx - ci * 14;
            float4 v = *(const float4*)(xs + (size_t)ci * 3136 + w4 * 4);
            tile[(w4 * 4 + 0) * 130 + ci] = f2bf(v.x);
            tile[(w4 * 4 + 1) * 130 + ci] = f2bf(v.y);
            tile[(w4 * 4 + 2) * 130 + ci] = f2bf(v.z);
            tile[(w4 * 4 + 3) * 130 + ci] = f2bf(v.w);
        }
    }
    __syncthreads();
#pragma unroll
    for (int it = 0; it < 4; ++it) {
        int k = it * 256 + tid;                 // 928 chunks of 16B
        if (k >= 928) break;
        int wq = k >> 4, cc = k & 15;
        uint4 v;
        if (wq == 0 || wq == 57) { v.x = v.y = v.z = v.w = 0u; }
        else {
            const unsigned short* p = &tile[(wq - 1) * 130 + cc * 8];
            union { unsigned short s[8]; uint4 u; } pk;
#pragma unroll
            for (int j = 0; j < 8; ++j) pk.s[j] = p[j];
            v = pk.u;
        }
        *(uint4*)(row + wq * 128 + cc * 8) = v;
    }
}

// -------- main: 4-wave 128x64-per-wave implicit GEMM, 256x128 tile ---------
// A from global (fragment-order wt, register double-buffer, plain loads);
// B via LDS 2-deep 8KB buffers. Halves h=0..35: h=(dh*3+dw)*4+q, 32 k each.
__global__ __launch_bounds__(256, 2) void conv_mfma(
    const unsigned short* __restrict__ xp,   // [32][58][58][128] bf16
    const unsigned short* __restrict__ wt,   // fragment-order, 589824 B
    const void* __restrict__ bias,           // [256] fp32 or bf16
    void* __restrict__ out,                  // [32][256][56][56] fp32 or bf16
    const void* __restrict__ xorig)          // for dtype sniff only
{
    __shared__ __align__(16) char lds[16384];   // 2 B-buffers x 8KB
    const int tid   = threadIdx.x;
    const int lane  = tid & 63;
    const int wv    = tid >> 6;        // 0..3
    const int bid   = blockIdx.x;
    const int ntile = (bid & 7) * 98 + (bid >> 3);   // XCD swizzle, 784=8x98

    const bool isbf = wave_detect_bf16((const unsigned int*)xorig);

    // ---- B staging setup (2 x 1KB chunks per wave per half) --------------
    const int clg  = (lane & 3) ^ ((lane >> 3) & 3);
    const int rsub = lane >> 2;
    unsigned sbB[2]; int dbB[2];
#pragma unroll
    for (int s = 0; s < 2; ++s) {
        const int c = wv * 2 + s;
        const int n = ntile * 128 + c * 16 + rsub;
        const int b = n / 3136, rem = n - b * 3136;
        const int hh = rem / 56, ww = rem - hh * 56;
        sbB[s] = (unsigned)(((b * 58 + hh) * 58 + ww) * 256 + clg * 16);
        dbB[s] = c * 1024;
    }

    // ---- fragment setup ---------------------------------------------------
    const int fr = lane & 15;
    const int ph = (lane >> 4) ^ ((fr >> 1) & 3);
    const int wm = wv >> 1;            // 0..1  (M: 128 couts per wave)
    const int wn = wv & 1;             // 0..1  (N: 64 cols per wave)
    const int bOff = (wn * 64 + fr) * 64 + ph * 16;   // + j*1024
    const int aSub = wm * 4096 + lane * 8;            // ushort units

    floatx4 acc[8][4] = {};
    short8 afA[8], afB[8];

    // ---- prologue: A(0)->afA (plain loads); stage B(0) into buf0 ---------
#pragma unroll
    for (int i_ = 0; i_ < 8; ++i_)
        afA[i_] = *(const short8*)(wt + aSub + i_ * 512);
    gl2lds16((const char*)xp + sbB[0], lds + dbB[0]);
    gl2lds16((const char*)xp + sbB[1], lds + dbB[1]);
    __builtin_amdgcn_s_waitcnt(0x3F70);   // vmcnt(0): B(0) landed
    __builtin_amdgcn_s_barrier();

// Body for half H (H <= 34): prefetch A(H+1)->AF_LOAD (plain loads,
// compiler-tracked), stage B(H+1) into buffer (H+1)&1, consume
// AF_USE=A(H) with B(H) fragments from buffer H&1, then a conservative
// vmcnt(0)+barrier (superset drain: B(H+1) and A(H+1) were issued a full
// MFMA block (~600cyc) earlier, so the drain is mostly covered; the
// second co-resident block covers the rest).
#define BODY(H, AF_USE, AF_LOAD)                                           \
  {                                                                        \
    {                                                                      \
      const unsigned short* aP = wt + (size_t)((H) + 1) * 8192 + aSub;     \
      _Pragma("unroll")                                                    \
      for (int i_ = 0; i_ < 8; ++i_)                                       \
        AF_LOAD[i_] = *(const short8*)(aP + i_ * 512);                     \
    }                                                                      \
    {                                                                      \
      char* sd = lds + (((H) + 1) & 1) * 8192;                             \
      const int hn = (H) + 1, off_ = hn >> 2, qq = hn & 3;                 \
      const int dh_ = off_ / 3, dw_ = off_ - dh_ * 3;                      \
      const int dB = (dh_ * 58 + dw_) * 256 + qq * 64;                     \
      gl2lds16((const char*)xp + sbB[0] + dB, sd + dbB[0]);                \
      gl2lds16((const char*)xp + sbB[1] + dB, sd + dbB[1]);                \
    }                                                                      \
    short8 bfr[4];                                                         \
    {                                                                      \
      const char* la = lds + ((H) & 1) * 8192;                             \
      bfr[0] = *(const short8*)(la + bOff);                                \
      bfr[1] = *(const short8*)(la + bOff + 1024);                         \
      bfr[2] = *(const short8*)(la + bOff + 2048);                         \
      bfr[3] = *(const short8*)(la + bOff + 3072);                         \
    }                                                                      \
    __builtin_amdgcn_s_setprio(1);                                         \
    _Pragma("unroll")                                                      \
    for (int i_ = 0; i_ < 8; ++i_) {                                       \
      _Pragma("unroll")                                                    \
      for (int j_ = 0; j_ < 4; ++j_)                                       \
        acc[i_][j_] = __builtin_amdgcn_mfma_f32_16x16x32_bf16(             \
            AF_USE[i_], bfr[j_], acc[i_][j_], 0, 0, 0);                    \
    }                                                                      \
    __builtin_amdgcn_s_setprio(0);                                         \
    __builtin_amdgcn_s_waitcnt(0x3F70);                                    \
    __builtin_amdgcn_s_barrier();                                          \
  }

    for (int h = 0; h < 34; h += 2) {
        BODY(h,     afA, afB);
        BODY(h + 1, afB, afA);
    }
    BODY(34, afA, afB);            // stages B(35), prefetches A(35)->afB
    // ---- h = 35: consume afB=A(35) with B(35) from buffer 1 --------------
    {
        const char* la = lds + 8192;
        short8 bfr[4];
        bfr[0] = *(const short8*)(la + bOff);
        bfr[1] = *(const short8*)(la + bOff + 1024);
        bfr[2] = *(const short8*)(la + bOff + 2048);
        bfr[3] = *(const short8*)(la + bOff + 3072);
#pragma unroll
        for (int i_ = 0; i_ < 8; ++i_)
#pragma unroll
            for (int j_ = 0; j_ < 4; ++j_)
                acc[i_][j_] = __builtin_amdgcn_mfma_f32_16x16x32_bf16(
                    afB[i_], bfr[j_], acc[i_][j_], 0, 0, 0);
    }

    // ---- epilogue: D[row=cout(quad*4+reg)][col=spatial(lane&15)] ----------
    const int q4 = (lane >> 4) << 2;
    int nb[4], ns[4];
#pragma unroll
    for (int j = 0; j < 4; ++j) {
        const int n = ntile * 128 + wn * 64 + j * 16 + fr;
        nb[j] = n / 3136;
        ns[j] = n - nb[j] * 3136;
    }
#pragma unroll
    for (int i = 0; i < 8; ++i) {
        const int co = wm * 128 + i * 16 + q4;
        float bv[4];
        if (isbf) {
            const ushort4 bb = *(const ushort4*)((const unsigned short*)bias + co);
            bv[0] = bf2f(bb.x); bv[1] = bf2f(bb.y);
            bv[2] = bf2f(bb.z); bv[3] = bf2f(bb.w);
        } else {
            const float4 bb = *(const float4*)((const float*)bias + co);
            bv[0] = bb.x; bv[1] = bb.y; bv[2] = bb.z; bv[3] = bb.w;
        }
#pragma unroll
        for (int j = 0; j < 4; ++j) {
#pragma unroll
            for (int r = 0; r < 4; ++r) {
                const float v = acc[i][j][r] + bv[r];
                const size_t o = (size_t)nb[j] * 802816 +
                                 (size_t)(co + r) * 3136 + ns[j];
                if (isbf) ((unsigned short*)out)[o] = f2bf(v);
                else      ((float*)out)[o] = v;
            }
        }
    }
}

// ---------------- fallback: naive direct conv fp32 (if ws too small) -------
__global__ void conv_naive(const float* __restrict__ x,
                           const float* __restrict__ w,
                           const float* __restrict__ bias,
                           float* __restrict__ out) {
    long long i = (long long)blockIdx.x * 256 + threadIdx.x;
    if (i >= 25690112LL) return;
    int wo = (int)(i % 56); long long t = i / 56;
    int ho = (int)(t % 56); t /= 56;
    int co = (int)(t % 256); int b = (int)(t / 256);
    float acc = bias[co];
    for (int ci = 0; ci < 128; ++ci)
        for (int dh = 0; dh < 3; ++dh) {
            int hi = ho + dh - 1; if ((unsigned)hi >= 56u) continue;
            for (int dw = 0; dw < 3; ++dw) {
                int wi = wo + dw - 1; if ((unsigned)wi >= 56u) continue;
                acc += x[((size_t)(b * 128 + ci) * 56 + hi) * 56 + wi] *
                       w[((co * 128 + ci) * 3 + dh) * 3 + dw];
            }
        }
    out[i] = acc;
}

extern "C" void kernel_launch(void* const* d_in, const int* in_sizes, int n_in,
                              void* d_out, int out_size, void* d_ws, size_t ws_size,
                              hipStream_t stream) {
    const void* x    = d_in[0];
    const void* w    = d_in[1];
    const void* bias = d_in[2];
    // d_in[3] = approximate (scalar, does not affect exact math) — unused.

    const size_t xp_bytes = (size_t)32 * 58 * 58 * 128 * 2;   // 27,557,888
    const size_t wt_off   = xp_bytes;
    const size_t wt_bytes = (size_t)9 * 256 * 128 * 2;        // 589,824
    const size_t need     = wt_off + wt_bytes;

    if (ws_size >= need) {
        unsigned short* xp = (unsigned short*)d_ws;
        unsigned short* wt = (unsigned short*)((char*)d_ws + wt_off);
        x_repack<<<32 * 58, 256, 0, stream>>>(x, xp);
        wt_repack<<<144, 256, 0, stream>>>(w, wt);
        conv_mfma<<<dim3(784, 1, 1), 256, 0, stream>>>(xp, wt, bias, d_out, x);
    } else {
        conv_naive<<<(25690112 + 255) / 256, 256, 0, stream>>>(
            (const float*)x, (const float*)w, (const float*)bias, (float*)d_out);
    }
}